// Round 2
// baseline (1215.894 us; speedup 1.0000x reference)
//
#include <hip/hip_runtime.h>
#include <stdint.h>

// Problem constants
#define B_   8
#define S_   4096
#define D_   1024
#define H_   16
#define HD_  64
#define M_   (B_ * S_)   // 32768 rows
#define N3   (3 * D_)    // 3072 fused QKV cols

using f32x4 = __attribute__((ext_vector_type(4))) float;
using s8v   = __attribute__((ext_vector_type(8))) short;
using u16x8 = __attribute__((ext_vector_type(8))) unsigned short;
using bf8v  = __attribute__((ext_vector_type(8))) __bf16;
using f32x4e = __attribute__((ext_vector_type(4))) float;

static __device__ __forceinline__ float bf2f(unsigned short u) {
  union { unsigned int i; float f; } x; x.i = ((unsigned int)u) << 16; return x.f;
}
static __device__ __forceinline__ unsigned short f2bf(float f) {
  union { float f; unsigned int i; } x; x.f = f;
  unsigned int r = x.i + 0x7fffu + ((x.i >> 16) & 1u);
  return (unsigned short)(r >> 16);
}

// ---- MFMA wrapper: tolerate either short8 or __bf16x8 builtin signature ----
template <typename T>
static __device__ __forceinline__ auto mfma_try(T a, T b, f32x4 c, int)
    -> decltype(__builtin_amdgcn_mfma_f32_16x16x32_bf16(a, b, c, 0, 0, 0)) {
  return __builtin_amdgcn_mfma_f32_16x16x32_bf16(a, b, c, 0, 0, 0);
}
template <typename T>
static __device__ __forceinline__ f32x4 mfma_try(T a, T b, f32x4 c, long) {
  return __builtin_amdgcn_mfma_f32_16x16x32_bf16(
      __builtin_bit_cast(bf8v, a), __builtin_bit_cast(bf8v, b), c, 0, 0, 0);
}
static __device__ __forceinline__ f32x4 mfma_bf16(s8v a, s8v b, f32x4 c) {
  return mfma_try(a, b, c, 0);
}

// ---- async global->LDS 16B ----
static __device__ __forceinline__ void gl_lds16(const void* g, void* l) {
  __builtin_amdgcn_global_load_lds(
      (const __attribute__((address_space(1))) void*)g,
      (__attribute__((address_space(3))) void*)l, 16, 0, 0);
}

// ================= X fp32 -> bf16 =================
__global__ __launch_bounds__(256) void cvt_bf16_k(const float* __restrict__ in,
                                                  unsigned short* __restrict__ out) {
  size_t i = ((size_t)blockIdx.x * 256 + threadIdx.x) * 8;
  f32x4e a = *(const f32x4e*)(in + i);
  f32x4e b = *(const f32x4e*)(in + i + 4);
  u16x8 o;
#pragma unroll
  for (int j = 0; j < 4; ++j) { o[j] = f2bf(a[j]); o[4 + j] = f2bf(b[j]); }
  *(u16x8*)(out + i) = o;
}

// ================= pack W^T (bf16) =================
// WT[mat][n][k] = W[k][n];  W row-major [1024][1024]
__global__ __launch_bounds__(256) void packWT_k(const float* __restrict__ Wq,
                                                const float* __restrict__ Wk,
                                                const float* __restrict__ Wv,
                                                unsigned short* __restrict__ WT) {
  __shared__ unsigned short tile[64][65];
  const float* W = blockIdx.z == 0 ? Wq : (blockIdx.z == 1 ? Wk : Wv);
  unsigned short* O = WT + (size_t)blockIdx.z * 1024 * 1024;
  const int tk = blockIdx.x * 64, tn = blockIdx.y * 64;
  const int t = threadIdx.x;
#pragma unroll
  for (int i = 0; i < 16; ++i) {
    int idx = i * 256 + t; int r = idx >> 6, c = idx & 63;  // r: k-local, c: n-local
    tile[c][r] = f2bf(W[(size_t)(tk + r) * 1024 + tn + c]);
  }
  __syncthreads();
#pragma unroll
  for (int i = 0; i < 16; ++i) {
    int idx = i * 256 + t; int r = idx >> 6, c = idx & 63;  // r: n-local, c: k-local
    O[(size_t)(tn + r) * 1024 + tk + c] = tile[r][c];
  }
}

__global__ void packbias_k(const float* __restrict__ bq, const float* __restrict__ bk,
                           const float* __restrict__ bv, float* __restrict__ bcat) {
  int i = blockIdx.x * 256 + threadIdx.x;
  if (i < 1024) bcat[i] = bq[i];
  else if (i < 2048) bcat[i] = bk[i - 1024];
  else if (i < 3072) bcat[i] = bv[i - 2048];
}

// ================= fused QKV GEMM =================
// C[M_][N3] (bf16) = A[M_][1024](bf16) * BT[N3][1024]^T (bf16) + bias
// 128x128 tile, BK=64, 4 waves (2x2 of 64x64), mfma 16x16x32.
__global__ __launch_bounds__(256) void gemm_qkv(const unsigned short* __restrict__ A,
                                                const unsigned short* __restrict__ BT,
                                                const float* __restrict__ bias,
                                                unsigned short* __restrict__ C) {
  __shared__ unsigned short As[128 * 64];
  __shared__ unsigned short Bs[128 * 64];
  const int t = threadIdx.x;
  const int w = t >> 6, l = t & 63;
  const int mrow0 = blockIdx.y * 128;
  const int ncol0 = blockIdx.x * 128;
  // staging coords: 32 rows x 64 cols per issue, 8 threads/row * 8 elems
  const int srow = t >> 3;          // 0..31
  const int scol = (t & 7) * 8;     // 0..56
  const unsigned short* Ag = A + (size_t)(mrow0 + srow) * 1024 + scol;
  const unsigned short* Bg = BT + (size_t)(ncol0 + srow) * 1024 + scol;
  unsigned short* Al = &As[srow * 64 + scol];
  unsigned short* Bl = &Bs[srow * 64 + scol];

  f32x4 acc[4][4];
#pragma unroll
  for (int m = 0; m < 4; ++m)
#pragma unroll
    for (int n = 0; n < 4; ++n) acc[m][n] = f32x4{0.f, 0.f, 0.f, 0.f};

  const int wr = (w >> 1) * 64, wc = (w & 1) * 64;
  const int fr = l & 15, fk = (l >> 4) * 8;

  for (int kt = 0; kt < 16; ++kt) {
    const int kk = kt * 64;
#pragma unroll
    for (int i = 0; i < 4; ++i) {
      gl_lds16(Ag + (size_t)(i * 32) * 1024 + kk, Al + i * 32 * 64);
      gl_lds16(Bg + (size_t)(i * 32) * 1024 + kk, Bl + i * 32 * 64);
    }
    __syncthreads();
#pragma unroll
    for (int ks = 0; ks < 2; ++ks) {
      s8v af[4], bf[4];
#pragma unroll
      for (int m = 0; m < 4; ++m)
        af[m] = *(const s8v*)&As[(wr + m * 16 + fr) * 64 + ks * 32 + fk];
#pragma unroll
      for (int n = 0; n < 4; ++n)
        bf[n] = *(const s8v*)&Bs[(wc + n * 16 + fr) * 64 + ks * 32 + fk];
#pragma unroll
      for (int m = 0; m < 4; ++m)
#pragma unroll
        for (int n = 0; n < 4; ++n)
          acc[m][n] = mfma_bf16(af[m], bf[n], acc[m][n]);
    }
    __syncthreads();
  }
  // epilogue: C/D layout col = l&15, row = (l>>4)*4 + i
  const int r4 = (l >> 4) * 4;
#pragma unroll
  for (int n = 0; n < 4; ++n) {
    const int gc = ncol0 + wc + n * 16 + fr;
    const float bv = bias[gc];
#pragma unroll
    for (int m = 0; m < 4; ++m)
#pragma unroll
      for (int i = 0; i < 4; ++i) {
        const int gr = mrow0 + wr + m * 16 + r4 + i;
        C[(size_t)gr * N3 + gc] = f2bf(acc[m][n][i] + bv);
      }
  }
}

// ================= pooling over sequence (Q) =================
// one block per (b,h): logits -> softmax -> gq[d] = sum_s alpha_s q[s][d]
__global__ __launch_bounds__(256) void pool_q(const unsigned short* __restrict__ QKV,
                                              const float* __restrict__ wql,
                                              const float* __restrict__ bql,
                                              float* __restrict__ gq) {
  __shared__ float L[S_];
  __shared__ float wsh[64];
  __shared__ float redA[4], redB[4];
  __shared__ float red2[256];
  const int t = threadIdx.x;
  const int bh = blockIdx.x;
  const int b = bh >> 4, h = bh & 15;
  const size_t base = ((size_t)b * S_) * N3 + h * 64;
  if (t < 64) wsh[t] = wql[t];
  __syncthreads();
  // phase 1: logits, 8 threads per row
  const int rsub = t >> 3, csub = (t & 7) * 8;
  const float bq = bql[0];
  for (int p = 0; p < 128; ++p) {
    int s = p * 32 + rsub;
    u16x8 v = *(const u16x8*)(QKV + base + (size_t)s * N3 + csub);
    float d = 0.f;
#pragma unroll
    for (int j = 0; j < 8; ++j) d += bf2f(v[j]) * wsh[csub + j];
    d += __shfl_xor(d, 1); d += __shfl_xor(d, 2); d += __shfl_xor(d, 4);
    if ((t & 7) == 0) L[s] = (d + bq) * 0.125f;
  }
  __syncthreads();
  // softmax over 4096
  float mx = -1e30f;
  for (int j = 0; j < 16; ++j) mx = fmaxf(mx, L[t + j * 256]);
  for (int off = 32; off; off >>= 1) mx = fmaxf(mx, __shfl_xor(mx, off));
  if ((t & 63) == 0) redA[t >> 6] = mx;
  __syncthreads();
  mx = fmaxf(fmaxf(redA[0], redA[1]), fmaxf(redA[2], redA[3]));
  float sm = 0.f;
  for (int j = 0; j < 16; ++j) sm += expf(L[t + j * 256] - mx);
  for (int off = 32; off; off >>= 1) sm += __shfl_xor(sm, off);
  if ((t & 63) == 0) redB[t >> 6] = sm;
  __syncthreads();
  const float inv = 1.f / (redB[0] + redB[1] + redB[2] + redB[3]);
  for (int j = 0; j < 16; ++j) {
    int s = t + j * 256;
    L[s] = expf(L[s] - mx) * inv;
  }
  __syncthreads();
  // phase 2: weighted sum; lane d, wave g
  const int d = t & 63, g = t >> 6;
  float acc = 0.f;
  for (int s = g; s < S_; s += 4)
    acc += L[s] * bf2f(QKV[base + (size_t)s * N3 + d]);
  red2[t] = acc;
  __syncthreads();
  if (t < 64) gq[bh * 64 + t] = red2[t] + red2[64 + t] + red2[128 + t] + red2[192 + t];
}

// ================= pooling over sequence (K, gated by gq) =================
__global__ __launch_bounds__(256) void pool_k(const unsigned short* __restrict__ QKV,
                                              const float* __restrict__ wkl,
                                              const float* __restrict__ bkl,
                                              const float* __restrict__ gq,
                                              float* __restrict__ gk) {
  __shared__ float L[S_];
  __shared__ float wsh[64];
  __shared__ float redA[4], redB[4];
  __shared__ float red2[256];
  const int t = threadIdx.x;
  const int bh = blockIdx.x;
  const int b = bh >> 4, h = bh & 15;
  const size_t base = ((size_t)b * S_) * N3 + 1024 + h * 64;  // K block
  if (t < 64) wsh[t] = gq[bh * 64 + t] * wkl[t];
  __syncthreads();
  const int rsub = t >> 3, csub = (t & 7) * 8;
  const float bk = bkl[0];
  for (int p = 0; p < 128; ++p) {
    int s = p * 32 + rsub;
    u16x8 v = *(const u16x8*)(QKV + base + (size_t)s * N3 + csub);
    float d = 0.f;
#pragma unroll
    for (int j = 0; j < 8; ++j) d += bf2f(v[j]) * wsh[csub + j];
    d += __shfl_xor(d, 1); d += __shfl_xor(d, 2); d += __shfl_xor(d, 4);
    if ((t & 7) == 0) L[s] = (d + bk) * 0.125f;
  }
  __syncthreads();
  float mx = -1e30f;
  for (int j = 0; j < 16; ++j) mx = fmaxf(mx, L[t + j * 256]);
  for (int off = 32; off; off >>= 1) mx = fmaxf(mx, __shfl_xor(mx, off));
  if ((t & 63) == 0) redA[t >> 6] = mx;
  __syncthreads();
  mx = fmaxf(fmaxf(redA[0], redA[1]), fmaxf(redA[2], redA[3]));
  float sm = 0.f;
  for (int j = 0; j < 16; ++j) sm += expf(L[t + j * 256] - mx);
  for (int off = 32; off; off >>= 1) sm += __shfl_xor(sm, off);
  if ((t & 63) == 0) redB[t >> 6] = sm;
  __syncthreads();
  const float inv = 1.f / (redB[0] + redB[1] + redB[2] + redB[3]);
  for (int j = 0; j < 16; ++j) {
    int s = t + j * 256;
    L[s] = expf(L[s] - mx) * inv;
  }
  __syncthreads();
  const int d = t & 63, g = t >> 6;
  float acc = 0.f;
  for (int s = g; s < S_; s += 4)
    acc += L[s] * bf2f(QKV[base + (size_t)s * N3 + d]);
  red2[t] = acc;
  __syncthreads();
  if (t < 64) gk[bh * 64 + t] = gq[bh * 64 + t] * (red2[t] + red2[64 + t] + red2[128 + t] + red2[192 + t]);
}

// ================= final: out = q + (v*gk) @ Wr + br =================
// block: (b,h) x 128-row chunk; 4 waves each own 32 rows; mfma 16x16x32, K=64.
__global__ __launch_bounds__(256) void final_out(const unsigned short* __restrict__ QKV,
                                                 const float* __restrict__ gk,
                                                 const float* __restrict__ Wr,
                                                 const float* __restrict__ br,
                                                 float* __restrict__ out) {
  __shared__ unsigned short Us[128 * 64];
  __shared__ float wrs[64 * 64];
  __shared__ float gks[64];
  const int t = threadIdx.x;
  const int w = t >> 6, l = t & 63;
  const int bh = blockIdx.y, sc = blockIdx.x;
  const int b = bh >> 4, h = bh & 15;
  const int s0 = sc * 128;
  if (t < 64) gks[t] = gk[bh * 64 + t];
#pragma unroll
  for (int i = 0; i < 16; ++i) wrs[i * 256 + t] = Wr[i * 256 + t];
  __syncthreads();
  // stage U = v * gk into LDS (bf16)
  const int rsub = t >> 3, csub = (t & 7) * 8;
  const size_t vbase = (((size_t)b * S_ + s0) * N3) + 2048 + h * 64;
#pragma unroll
  for (int i = 0; i < 4; ++i) {
    int r = i * 32 + rsub;
    u16x8 v = *(const u16x8*)(QKV + vbase + (size_t)r * N3 + csub);
    u16x8 u;
#pragma unroll
    for (int j = 0; j < 8; ++j) u[j] = f2bf(bf2f(v[j]) * gks[csub + j]);
    *(u16x8*)&Us[r * 64 + csub] = u;
  }
  // B frags from Wr (B[k][c] = Wr[k*64+c])
  const int fr = l & 15, fk = (l >> 4) * 8;
  s8v bfrag[2][4];
#pragma unroll
  for (int ks = 0; ks < 2; ++ks)
#pragma unroll
    for (int nf = 0; nf < 4; ++nf) {
      s8v tmp;
#pragma unroll
      for (int j = 0; j < 8; ++j)
        tmp[j] = (short)f2bf(wrs[(ks * 32 + fk + j) * 64 + nf * 16 + fr]);
      bfrag[ks][nf] = tmp;
    }
  __syncthreads();
  f32x4 acc[2][4];
#pragma unroll
  for (int rf = 0; rf < 2; ++rf)
#pragma unroll
    for (int nf = 0; nf < 4; ++nf) acc[rf][nf] = f32x4{0.f, 0.f, 0.f, 0.f};
#pragma unroll
  for (int ks = 0; ks < 2; ++ks) {
    s8v af[2];
#pragma unroll
    for (int rf = 0; rf < 2; ++rf)
      af[rf] = *(const s8v*)&Us[(w * 32 + rf * 16 + fr) * 64 + ks * 32 + fk];
#pragma unroll
    for (int rf = 0; rf < 2; ++rf)
#pragma unroll
      for (int nf = 0; nf < 4; ++nf)
        acc[rf][nf] = mfma_bf16(af[rf], bfrag[ks][nf], acc[rf][nf]);
  }
  // epilogue: out = q + acc + br
  const int r4 = (l >> 4) * 4;
#pragma unroll
  for (int rf = 0; rf < 2; ++rf)
#pragma unroll
    for (int nf = 0; nf < 4; ++nf)
#pragma unroll
      for (int i = 0; i < 4; ++i) {
        int srow = s0 + w * 32 + rf * 16 + r4 + i;
        int dcol = nf * 16 + fr;
        size_t row = (size_t)b * S_ + srow;
        float q = bf2f(QKV[row * N3 + h * 64 + dcol]);
        out[row * 1024 + h * 64 + dcol] = q + acc[rf][nf][i] + br[dcol];
      }
}

extern "C" void kernel_launch(void* const* d_in, const int* in_sizes, int n_in,
                              void* d_out, int out_size, void* d_ws, size_t ws_size,
                              hipStream_t stream) {
  const float* X   = (const float*)d_in[0];
  const float* Wq  = (const float*)d_in[1];
  const float* bq  = (const float*)d_in[2];
  const float* Wk  = (const float*)d_in[3];
  const float* bk  = (const float*)d_in[4];
  const float* Wv  = (const float*)d_in[5];
  const float* bv  = (const float*)d_in[6];
  const float* wql = (const float*)d_in[7];
  const float* bql = (const float*)d_in[8];
  const float* wkl = (const float*)d_in[9];
  const float* bkl = (const float*)d_in[10];
  const float* Wr  = (const float*)d_in[11];
  const float* br  = (const float*)d_in[12];
  float* out = (float*)d_out;

  char* ws = (char*)d_ws;
  unsigned short* Xb  = (unsigned short*)ws;                    // 67,108,864 B
  unsigned short* WT  = (unsigned short*)(ws + 67108864);       //  6,291,456 B
  float* bcat         = (float*)(ws + 73400320);                //     12,288 B
  unsigned short* QKV = (unsigned short*)(ws + 73412608);       // 201,326,592 B
  float* gq           = (float*)(ws + 274739200);               //     32,768 B
  float* gk           = (float*)(ws + 274771968);               //     32,768 B

  hipLaunchKernelGGL(cvt_bf16_k, dim3(16384), dim3(256), 0, stream, X, Xb);
  hipLaunchKernelGGL(packWT_k, dim3(16, 16, 3), dim3(256), 0, stream, Wq, Wk, Wv, WT);
  hipLaunchKernelGGL(packbias_k, dim3(12), dim3(256), 0, stream, bq, bk, bv, bcat);
  hipLaunchKernelGGL(gemm_qkv, dim3(24, 256), dim3(256), 0, stream, Xb, WT, bcat, QKV);
  hipLaunchKernelGGL(pool_q, dim3(128), dim3(256), 0, stream, QKV, wql, bql, gq);
  hipLaunchKernelGGL(pool_k, dim3(128), dim3(256), 0, stream, QKV, wkl, bkl, gq, gk);
  hipLaunchKernelGGL(final_out, dim3(32, 128), dim3(256), 0, stream, QKV, gk, Wr, br, out);
}

// Round 3
// 659.091 us; speedup vs baseline: 1.8448x; 1.8448x over previous
//
#include <hip/hip_runtime.h>
#include <stdint.h>

// Problem constants
#define B_   8
#define S_   4096
#define D_   1024
#define H_   16
#define HD_  64
#define M_   (B_ * S_)   // 32768 rows
#define N3   (3 * D_)    // 3072 fused QKV cols

using f32x4 = __attribute__((ext_vector_type(4))) float;
using s8v   = __attribute__((ext_vector_type(8))) short;
using u16x8 = __attribute__((ext_vector_type(8))) unsigned short;
using bf8v  = __attribute__((ext_vector_type(8))) __bf16;

static __device__ __forceinline__ float bf2f(unsigned short u) {
  union { unsigned int i; float f; } x; x.i = ((unsigned int)u) << 16; return x.f;
}
static __device__ __forceinline__ unsigned short f2bf(float f) {
  union { float f; unsigned int i; } x; x.f = f;
  unsigned int r = x.i + 0x7fffu + ((x.i >> 16) & 1u);
  return (unsigned short)(r >> 16);
}

// ---- MFMA wrapper: tolerate either short8 or __bf16x8 builtin signature ----
template <typename T>
static __device__ __forceinline__ auto mfma_try(T a, T b, f32x4 c, int)
    -> decltype(__builtin_amdgcn_mfma_f32_16x16x32_bf16(a, b, c, 0, 0, 0)) {
  return __builtin_amdgcn_mfma_f32_16x16x32_bf16(a, b, c, 0, 0, 0);
}
template <typename T>
static __device__ __forceinline__ f32x4 mfma_try(T a, T b, f32x4 c, long) {
  return __builtin_amdgcn_mfma_f32_16x16x32_bf16(
      __builtin_bit_cast(bf8v, a), __builtin_bit_cast(bf8v, b), c, 0, 0, 0);
}
static __device__ __forceinline__ f32x4 mfma_bf16(s8v a, s8v b, f32x4 c) {
  return mfma_try(a, b, c, 0);
}

// ---- async global->LDS 16B ----
static __device__ __forceinline__ void gl_lds16(const void* g, void* l) {
  __builtin_amdgcn_global_load_lds(
      (const __attribute__((address_space(1))) void*)g,
      (__attribute__((address_space(3))) void*)l, 16, 0, 0);
}

// ================= X fp32 -> bf16 =================
__global__ __launch_bounds__(256) void cvt_bf16_k(const float* __restrict__ in,
                                                  unsigned short* __restrict__ out) {
  size_t i = ((size_t)blockIdx.x * 256 + threadIdx.x) * 8;
  f32x4 a = *(const f32x4*)(in + i);
  f32x4 b = *(const f32x4*)(in + i + 4);
  u16x8 o;
#pragma unroll
  for (int j = 0; j < 4; ++j) { o[j] = f2bf(a[j]); o[4 + j] = f2bf(b[j]); }
  *(u16x8*)(out + i) = o;
}

// ================= pack W^T (bf16) =================
__global__ __launch_bounds__(256) void packWT_k(const float* __restrict__ Wq,
                                                const float* __restrict__ Wk,
                                                const float* __restrict__ Wv,
                                                unsigned short* __restrict__ WT) {
  __shared__ unsigned short tile[64][65];
  const float* W = blockIdx.z == 0 ? Wq : (blockIdx.z == 1 ? Wk : Wv);
  unsigned short* O = WT + (size_t)blockIdx.z * 1024 * 1024;
  const int tk = blockIdx.x * 64, tn = blockIdx.y * 64;
  const int t = threadIdx.x;
#pragma unroll
  for (int i = 0; i < 16; ++i) {
    int idx = i * 256 + t; int r = idx >> 6, c = idx & 63;
    tile[c][r] = f2bf(W[(size_t)(tk + r) * 1024 + tn + c]);
  }
  __syncthreads();
#pragma unroll
  for (int i = 0; i < 16; ++i) {
    int idx = i * 256 + t; int r = idx >> 6, c = idx & 63;
    O[(size_t)(tn + r) * 1024 + tk + c] = tile[r][c];
  }
}

__global__ void packbias_k(const float* __restrict__ bq, const float* __restrict__ bk,
                           const float* __restrict__ bv, float* __restrict__ bcat) {
  int i = blockIdx.x * 256 + threadIdx.x;
  if (i < 1024) bcat[i] = bq[i];
  else if (i < 2048) bcat[i] = bk[i - 1024];
  else if (i < 3072) bcat[i] = bv[i - 2048];
}

// ================= fused QKV GEMM (m97 structure) =================
__global__ __launch_bounds__(256) void gemm_qkv(const unsigned short* __restrict__ A,
                                                const unsigned short* __restrict__ BT,
                                                const float* __restrict__ bias,
                                                unsigned short* __restrict__ C) {
  __shared__ unsigned short As[128 * 64];
  __shared__ unsigned short Bs[128 * 64];
  const int t = threadIdx.x;
  const int w = t >> 6, l = t & 63;
  const int mrow0 = blockIdx.y * 128;
  const int ncol0 = blockIdx.x * 128;
  const int srow = t >> 3;
  const int scol = (t & 7) * 8;
  const unsigned short* Ag = A + (size_t)(mrow0 + srow) * 1024 + scol;
  const unsigned short* Bg = BT + (size_t)(ncol0 + srow) * 1024 + scol;
  unsigned short* Al = &As[srow * 64 + scol];
  unsigned short* Bl = &Bs[srow * 64 + scol];

  f32x4 acc[4][4];
#pragma unroll
  for (int m = 0; m < 4; ++m)
#pragma unroll
    for (int n = 0; n < 4; ++n) acc[m][n] = f32x4{0.f, 0.f, 0.f, 0.f};

  const int wr = (w >> 1) * 64, wc = (w & 1) * 64;
  const int fr = l & 15, fk = (l >> 4) * 8;

  for (int kt = 0; kt < 16; ++kt) {
    const int kk = kt * 64;
#pragma unroll
    for (int i = 0; i < 4; ++i) {
      gl_lds16(Ag + (size_t)(i * 32) * 1024 + kk, Al + i * 32 * 64);
      gl_lds16(Bg + (size_t)(i * 32) * 1024 + kk, Bl + i * 32 * 64);
    }
    __syncthreads();
#pragma unroll
    for (int ks = 0; ks < 2; ++ks) {
      s8v af[4], bf[4];
#pragma unroll
      for (int m = 0; m < 4; ++m)
        af[m] = *(const s8v*)&As[(wr + m * 16 + fr) * 64 + ks * 32 + fk];
#pragma unroll
      for (int n = 0; n < 4; ++n)
        bf[n] = *(const s8v*)&Bs[(wc + n * 16 + fr) * 64 + ks * 32 + fk];
#pragma unroll
      for (int m = 0; m < 4; ++m)
#pragma unroll
        for (int n = 0; n < 4; ++n)
          acc[m][n] = mfma_bf16(af[m], bf[n], acc[m][n]);
    }
    __syncthreads();
  }
  const int r4 = (l >> 4) * 4;
#pragma unroll
  for (int n = 0; n < 4; ++n) {
    const int gc = ncol0 + wc + n * 16 + fr;
    const float bb = bias[gc];
#pragma unroll
    for (int m = 0; m < 4; ++m)
#pragma unroll
      for (int i = 0; i < 4; ++i) {
        const int gr = mrow0 + wr + m * 16 + r4 + i;
        C[(size_t)gr * N3 + gc] = f2bf(acc[m][n][i] + bb);
      }
  }
}

// ================= pooling pipeline =================
// Stage 1: logits. One wave per row; lane covers 16 contiguous cols.
// L layout: [b][s][h] -> L[(b*S+s)*16 + h]
template <int GATED>
__global__ __launch_bounds__(256) void plog_k(const unsigned short* __restrict__ QKV,
                                              const float* __restrict__ wvec,
                                              const float* __restrict__ bias,
                                              float* __restrict__ L, int off) {
  const int t = threadIdx.x;
  const int rg = blockIdx.x * 4 + (t >> 6);   // global row 0..32767
  const int l = t & 63;
  const size_t base = (size_t)rg * N3 + off;
  u16x8 v0 = *(const u16x8*)(QKV + base + l * 16);
  u16x8 v1 = *(const u16x8*)(QKV + base + l * 16 + 8);
  const int h = l >> 2;
  const float* w;
  if (GATED) w = wvec + (((size_t)(rg >> 12) * 16 + h) * 64) + (l & 3) * 16;
  else       w = wvec + (l & 3) * 16;
  float d = 0.f;
#pragma unroll
  for (int j = 0; j < 8; ++j) d += bf2f(v0[j]) * w[j];
#pragma unroll
  for (int j = 0; j < 8; ++j) d += bf2f(v1[j]) * w[8 + j];
  d += __shfl_xor(d, 1); d += __shfl_xor(d, 2);
  if ((l & 3) == 0) L[(size_t)rg * 16 + h] = (d + bias[0]) * 0.125f;
}

// Stage 2: per-(b,h) softmax stats (max, 1/sum). 128 blocks.
__global__ __launch_bounds__(256) void pstats_k(const float* __restrict__ L,
                                                float* __restrict__ stats) {
  __shared__ float redm[4], reds[4];
  const int t = threadIdx.x;
  const int bh = blockIdx.x;
  const int b = bh >> 4, h = bh & 15;
  float vals[16];
  float mx = -1e30f;
#pragma unroll
  for (int j = 0; j < 16; ++j) {
    vals[j] = L[((size_t)b * S_ + t + j * 256) * 16 + h];
    mx = fmaxf(mx, vals[j]);
  }
  for (int off = 32; off; off >>= 1) mx = fmaxf(mx, __shfl_xor(mx, off));
  if ((t & 63) == 0) redm[t >> 6] = mx;
  __syncthreads();
  mx = fmaxf(fmaxf(redm[0], redm[1]), fmaxf(redm[2], redm[3]));
  float sm = 0.f;
#pragma unroll
  for (int j = 0; j < 16; ++j) sm += expf(vals[j] - mx);
  for (int off = 32; off; off >>= 1) sm += __shfl_xor(sm, off);
  if ((t & 63) == 0) reds[t >> 6] = sm;
  __syncthreads();
  if (t == 0) {
    stats[bh * 2] = mx;
    stats[bh * 2 + 1] = 1.f / (reds[0] + reds[1] + reds[2] + reds[3]);
  }
}

// Stage 3: partial weighted sums. grid (16 chunks, 128 bh); lane=col, wave strides rows.
__global__ __launch_bounds__(256) void psum_k(const unsigned short* __restrict__ QKV,
                                              const float* __restrict__ L,
                                              const float* __restrict__ stats,
                                              float* __restrict__ pg, int off) {
  __shared__ float red2[256];
  const int t = threadIdx.x;
  const int c = blockIdx.x, bh = blockIdx.y;
  const int b = bh >> 4, h = bh & 15;
  const float MX = stats[bh * 2], INV = stats[bh * 2 + 1];
  const int w = t >> 6, d = t & 63;
  float acc = 0.f;
  const int s0 = c * 256 + w * 64;
#pragma unroll 4
  for (int i = 0; i < 64; ++i) {
    const size_t row = (size_t)b * S_ + s0 + i;
    const float a = expf(L[row * 16 + h] - MX) * INV;
    acc += a * bf2f(QKV[row * N3 + off + h * 64 + d]);
  }
  red2[t] = acc;
  __syncthreads();
  if (t < 64)
    pg[((size_t)bh * 16 + c) * 64 + t] =
        red2[t] + red2[64 + t] + red2[128 + t] + red2[192 + t];
}

// Stage 4a (Q): gq = fold chunks; weffK = gq * wkl
__global__ __launch_bounds__(256) void predq_k(const float* __restrict__ pg,
                                               const float* __restrict__ wkl,
                                               float* __restrict__ gq,
                                               float* __restrict__ weffK) {
  const int idx = blockIdx.x * 256 + threadIdx.x;   // 8192 total
  const int bh = idx >> 6, d = idx & 63;
  float s = 0.f;
#pragma unroll
  for (int c = 0; c < 16; ++c) s += pg[((size_t)bh * 16 + c) * 64 + d];
  gq[idx] = s;
  weffK[idx] = s * wkl[d];
}

// Stage 4b (K): gk = gq * fold
__global__ __launch_bounds__(256) void predk_k(const float* __restrict__ pg,
                                               const float* __restrict__ gq,
                                               float* __restrict__ gk) {
  const int idx = blockIdx.x * 256 + threadIdx.x;
  const int bh = idx >> 6, d = idx & 63;
  float s = 0.f;
#pragma unroll
  for (int c = 0; c < 16; ++c) s += pg[((size_t)bh * 16 + c) * 64 + d];
  gk[idx] = gq[idx] * s;
}

// ================= final: out = q + (v*gk) @ Wr + br =================
__global__ __launch_bounds__(256) void final_out(const unsigned short* __restrict__ QKV,
                                                 const float* __restrict__ gk,
                                                 const float* __restrict__ Wr,
                                                 const float* __restrict__ br,
                                                 float* __restrict__ out) {
  __shared__ unsigned short Us[128 * 64];
  __shared__ float wrs[64 * 64];
  __shared__ float gks[64];
  const int t = threadIdx.x;
  const int w = t >> 6, l = t & 63;
  const int bh = blockIdx.y, sc = blockIdx.x;
  const int b = bh >> 4, h = bh & 15;
  const int s0 = sc * 128;
  if (t < 64) gks[t] = gk[bh * 64 + t];
#pragma unroll
  for (int i = 0; i < 16; ++i) wrs[i * 256 + t] = Wr[i * 256 + t];
  __syncthreads();
  const int rsub = t >> 3, csub = (t & 7) * 8;
  const size_t vbase = (((size_t)b * S_ + s0) * N3) + 2048 + h * 64;
#pragma unroll
  for (int i = 0; i < 4; ++i) {
    int r = i * 32 + rsub;
    u16x8 v = *(const u16x8*)(QKV + vbase + (size_t)r * N3 + csub);
    u16x8 u;
#pragma unroll
    for (int j = 0; j < 8; ++j) u[j] = f2bf(bf2f(v[j]) * gks[csub + j]);
    *(u16x8*)&Us[r * 64 + csub] = u;
  }
  const int fr = l & 15, fk = (l >> 4) * 8;
  s8v bfrag[2][4];
#pragma unroll
  for (int ks = 0; ks < 2; ++ks)
#pragma unroll
    for (int nf = 0; nf < 4; ++nf) {
      s8v tmp;
#pragma unroll
      for (int j = 0; j < 8; ++j)
        tmp[j] = (short)f2bf(wrs[(ks * 32 + fk + j) * 64 + nf * 16 + fr]);
      bfrag[ks][nf] = tmp;
    }
  __syncthreads();
  f32x4 acc[2][4];
#pragma unroll
  for (int rf = 0; rf < 2; ++rf)
#pragma unroll
    for (int nf = 0; nf < 4; ++nf) acc[rf][nf] = f32x4{0.f, 0.f, 0.f, 0.f};
#pragma unroll
  for (int ks = 0; ks < 2; ++ks) {
    s8v af[2];
#pragma unroll
    for (int rf = 0; rf < 2; ++rf)
      af[rf] = *(const s8v*)&Us[(w * 32 + rf * 16 + fr) * 64 + ks * 32 + fk];
#pragma unroll
    for (int rf = 0; rf < 2; ++rf)
#pragma unroll
      for (int nf = 0; nf < 4; ++nf)
        acc[rf][nf] = mfma_bf16(af[rf], bfrag[ks][nf], acc[rf][nf]);
  }
  const int r4 = (l >> 4) * 4;
#pragma unroll
  for (int rf = 0; rf < 2; ++rf)
#pragma unroll
    for (int nf = 0; nf < 4; ++nf)
#pragma unroll
      for (int i = 0; i < 4; ++i) {
        int srow = s0 + w * 32 + rf * 16 + r4 + i;
        int dcol = nf * 16 + fr;
        size_t row = (size_t)b * S_ + srow;
        float q = bf2f(QKV[row * N3 + h * 64 + dcol]);
        out[row * 1024 + h * 64 + dcol] = q + acc[rf][nf][i] + br[dcol];
      }
}

extern "C" void kernel_launch(void* const* d_in, const int* in_sizes, int n_in,
                              void* d_out, int out_size, void* d_ws, size_t ws_size,
                              hipStream_t stream) {
  const float* X   = (const float*)d_in[0];
  const float* Wq  = (const float*)d_in[1];
  const float* bq  = (const float*)d_in[2];
  const float* Wk  = (const float*)d_in[3];
  const float* bk  = (const float*)d_in[4];
  const float* Wv  = (const float*)d_in[5];
  const float* bv  = (const float*)d_in[6];
  const float* wql = (const float*)d_in[7];
  const float* bql = (const float*)d_in[8];
  const float* wkl = (const float*)d_in[9];
  const float* bkl = (const float*)d_in[10];
  const float* Wr  = (const float*)d_in[11];
  const float* br  = (const float*)d_in[12];
  float* out = (float*)d_out;

  char* ws = (char*)d_ws;
  // [0, 64MB): Xb during GEMM phase; pool scratch afterwards (Xb is dead then).
  unsigned short* Xb  = (unsigned short*)ws;
  unsigned short* WT  = (unsigned short*)(ws + 67108864);       // 6 MB
  float* bcat         = (float*)(ws + 73400320);                // 12 KB
  unsigned short* QKV = (unsigned short*)(ws + 73412608);       // 192 MB
  // pool scratch overlapping Xb region:
  float* Lq    = (float*)(ws + 0);                              // 2 MB
  float* Lk    = (float*)(ws + 2097152);                        // 2 MB
  float* pgq   = (float*)(ws + 4194304);                        // 512 KB
  float* pgk   = (float*)(ws + 4718592);                        // 512 KB
  float* statsQ= (float*)(ws + 5242880);                        // 1 KB
  float* statsK= (float*)(ws + 5246976);                        // 1 KB
  float* gq    = (float*)(ws + 6291456);                        // 32 KB
  float* weffK = (float*)(ws + 6324224);                        // 32 KB
  float* gk    = (float*)(ws + 6356992);                        // 32 KB

  hipLaunchKernelGGL(cvt_bf16_k, dim3(16384), dim3(256), 0, stream, X, Xb);
  hipLaunchKernelGGL(packWT_k, dim3(16, 16, 3), dim3(256), 0, stream, Wq, Wk, Wv, WT);
  hipLaunchKernelGGL(packbias_k, dim3(12), dim3(256), 0, stream, bq, bk, bv, bcat);
  hipLaunchKernelGGL(gemm_qkv, dim3(24, 256), dim3(256), 0, stream, Xb, WT, bcat, QKV);

  // Q pooling
  hipLaunchKernelGGL((plog_k<0>), dim3(8192), dim3(256), 0, stream, QKV, wql, bql, Lq, 0);
  hipLaunchKernelGGL(pstats_k, dim3(128), dim3(256), 0, stream, Lq, statsQ);
  hipLaunchKernelGGL(psum_k, dim3(16, 128), dim3(256), 0, stream, QKV, Lq, statsQ, pgq, 0);
  hipLaunchKernelGGL(predq_k, dim3(32), dim3(256), 0, stream, pgq, wkl, gq, weffK);
  // K pooling (gated)
  hipLaunchKernelGGL((plog_k<1>), dim3(8192), dim3(256), 0, stream, QKV, weffK, bkl, Lk, 1024);
  hipLaunchKernelGGL(pstats_k, dim3(128), dim3(256), 0, stream, Lk, statsK);
  hipLaunchKernelGGL(psum_k, dim3(16, 128), dim3(256), 0, stream, QKV, Lk, statsK, pgk, 1024);
  hipLaunchKernelGGL(predk_k, dim3(32), dim3(256), 0, stream, pgk, gq, gk);

  hipLaunchKernelGGL(final_out, dim3(32, 128), dim3(256), 0, stream, QKV, gk, Wr, br, out);
}

// Round 5
// 624.018 us; speedup vs baseline: 1.9485x; 1.0562x over previous
//
#include <hip/hip_runtime.h>
#include <stdint.h>

// Problem constants
#define B_   8
#define S_   4096
#define D_   1024
#define H_   16
#define HD_  64
#define M_   (B_ * S_)   // 32768 rows
#define N3   (3 * D_)    // 3072 fused QKV cols

using f32x4 = __attribute__((ext_vector_type(4))) float;
using s8v   = __attribute__((ext_vector_type(8))) short;
using u16x8 = __attribute__((ext_vector_type(8))) unsigned short;
using bf8v  = __attribute__((ext_vector_type(8))) __bf16;

static __device__ __forceinline__ float bf2f(unsigned short u) {
  union { unsigned int i; float f; } x; x.i = ((unsigned int)u) << 16; return x.f;
}
static __device__ __forceinline__ unsigned short f2bf(float f) {
  union { float f; unsigned int i; } x; x.f = f;
  unsigned int r = x.i + 0x7fffu + ((x.i >> 16) & 1u);
  return (unsigned short)(r >> 16);
}

// ---- MFMA wrapper: tolerate either short8 or __bf16x8 builtin signature ----
template <typename T>
static __device__ __forceinline__ auto mfma_try(T a, T b, f32x4 c, int)
    -> decltype(__builtin_amdgcn_mfma_f32_16x16x32_bf16(a, b, c, 0, 0, 0)) {
  return __builtin_amdgcn_mfma_f32_16x16x32_bf16(a, b, c, 0, 0, 0);
}
template <typename T>
static __device__ __forceinline__ f32x4 mfma_try(T a, T b, f32x4 c, long) {
  return __builtin_amdgcn_mfma_f32_16x16x32_bf16(
      __builtin_bit_cast(bf8v, a), __builtin_bit_cast(bf8v, b), c, 0, 0, 0);
}
static __device__ __forceinline__ f32x4 mfma_bf16(s8v a, s8v b, f32x4 c) {
  return mfma_try(a, b, c, 0);
}

// ---- async global->LDS 16B ----
static __device__ __forceinline__ void gl_lds16(const void* g, void* l) {
  __builtin_amdgcn_global_load_lds(
      (const __attribute__((address_space(1))) void*)g,
      (__attribute__((address_space(3))) void*)l, 16, 0, 0);
}

// ================= X fp32 -> bf16 =================
__global__ __launch_bounds__(256) void cvt_bf16_k(const float* __restrict__ in,
                                                  unsigned short* __restrict__ out) {
  size_t i = ((size_t)blockIdx.x * 256 + threadIdx.x) * 8;
  f32x4 a = *(const f32x4*)(in + i);
  f32x4 b = *(const f32x4*)(in + i + 4);
  u16x8 o;
#pragma unroll
  for (int j = 0; j < 4; ++j) { o[j] = f2bf(a[j]); o[4 + j] = f2bf(b[j]); }
  *(u16x8*)(out + i) = o;
}

// ================= pack W^T (bf16) =================
__global__ __launch_bounds__(256) void packWT_k(const float* __restrict__ Wq,
                                                const float* __restrict__ Wk,
                                                const float* __restrict__ Wv,
                                                unsigned short* __restrict__ WT) {
  __shared__ unsigned short tile[64][65];
  const float* W = blockIdx.z == 0 ? Wq : (blockIdx.z == 1 ? Wk : Wv);
  unsigned short* O = WT + (size_t)blockIdx.z * 1024 * 1024;
  const int tk = blockIdx.x * 64, tn = blockIdx.y * 64;
  const int t = threadIdx.x;
#pragma unroll
  for (int i = 0; i < 16; ++i) {
    int idx = i * 256 + t; int r = idx >> 6, c = idx & 63;
    tile[c][r] = f2bf(W[(size_t)(tk + r) * 1024 + tn + c]);
  }
  __syncthreads();
#pragma unroll
  for (int i = 0; i < 16; ++i) {
    int idx = i * 256 + t; int r = idx >> 6, c = idx & 63;
    O[(size_t)(tn + r) * 1024 + tk + c] = tile[r][c];
  }
}

__global__ void packbias_k(const float* __restrict__ bq, const float* __restrict__ bk,
                           const float* __restrict__ bv, float* __restrict__ bcat) {
  int i = blockIdx.x * 256 + threadIdx.x;
  if (i < 1024) bcat[i] = bq[i];
  else if (i < 2048) bcat[i] = bk[i - 1024];
  else if (i < 3072) bcat[i] = bv[i - 2048];
}

// ================= 256x256 counted-vmcnt GEMM =================
// LDS (128KB dynamic): buf0 {A[2][256][64B] swz, B same} buf1 {...}
// A-tile region: [kh][row][slot] where slot holds global k-group kh*4 + (slot ^ (row&3)).
// 2 super-phases per K-tile (kk=0,1); each stages kt+1's matching k-half, vmcnt(4)+barrier.
static __device__ __forceinline__ void stage_half(const unsigned short* __restrict__ g,
                                                  int grow0, int ktile, int kh,
                                                  char* lds_region, int t) {
#pragma unroll
  for (int j = 0; j < 2; ++j) {
    const int li = j * 512 + t;           // 0..1023, lane-consecutive per wave-load
    const int row = li >> 2, p = li & 3;
    const int sg = kh * 4 + (p ^ (row & 3));
    const unsigned short* src = g + (size_t)(grow0 + row) * 1024 + ktile * 64 + sg * 8;
    gl_lds16(src, lds_region + kh * 16384 + li * 16);
  }
}

__global__ __launch_bounds__(512, 2) void gemm256(const unsigned short* __restrict__ A,
                                                  const unsigned short* __restrict__ BT,
                                                  const float* __restrict__ bias,
                                                  unsigned short* __restrict__ C) {
  extern __shared__ char smem[];   // 131072 bytes
  const int t = threadIdx.x;
  const int w = t >> 6, l = t & 63;
  // XCD-aware bijective swizzle (nwg = 1536, divisible by 8)
  int bid = blockIdx.x;
  const int cpx = gridDim.x >> 3;
  bid = (bid & 7) * cpx + (bid >> 3);
  const int by = bid & 127;            // M block
  const int bx = bid >> 7;             // N block
  const int mrow0 = by * 256, ncol0 = bx * 256;
  const int wr = w >> 2, wc = w & 3;   // wave grid 2 (M) x 4 (N)
  const int fr = l & 15;
  const int p_read = (((l >> 4) ^ (fr & 3)) << 4);  // swizzled 16B slot byte-offset

  f32x4 acc[8][4];
#pragma unroll
  for (int m = 0; m < 8; ++m)
#pragma unroll
    for (int n = 0; n < 4; ++n) acc[m][n] = f32x4{0.f, 0.f, 0.f, 0.f};

  // Prologue: stage tile 0 (kh0 then kh1); vmcnt(4) leaves kh1 in flight.
  stage_half(A,  mrow0, 0, 0, smem, t);
  stage_half(BT, ncol0, 0, 0, smem + 32768, t);
  stage_half(A,  mrow0, 0, 1, smem, t);
  stage_half(BT, ncol0, 0, 1, smem + 32768, t);
  asm volatile("s_waitcnt vmcnt(4)" ::: "memory");
  __builtin_amdgcn_s_barrier();
  __builtin_amdgcn_sched_barrier(0);

  const int arow = wr * 128 + fr;      // + m*16
  const int brow = wc * 64 + fr;       // + n*16

  for (int kt = 0; kt < 15; ++kt) {
    const int base_rd = (kt & 1) * 65536;
    const int base_wr = base_rd ^ 65536;
#pragma unroll
    for (int kk = 0; kk < 2; ++kk) {
      s8v af[8], bfv[4];
#pragma unroll
      for (int m = 0; m < 8; ++m)
        af[m] = *(const s8v*)(smem + base_rd + kk * 16384 + (arow + m * 16) * 64 + p_read);
#pragma unroll
      for (int n = 0; n < 4; ++n)
        bfv[n] = *(const s8v*)(smem + base_rd + 32768 + kk * 16384 + (brow + n * 16) * 64 + p_read);
      // stage next tile's matching k-half while reading/computing this one
      stage_half(A,  mrow0, kt + 1, kk, smem + base_wr, t);
      stage_half(BT, ncol0, kt + 1, kk, smem + base_wr + 32768, t);
      __builtin_amdgcn_s_setprio(1);
#pragma unroll
      for (int m = 0; m < 8; ++m)
#pragma unroll
        for (int n = 0; n < 4; ++n)
          acc[m][n] = mfma_bf16(af[m], bfv[n], acc[m][n]);
      __builtin_amdgcn_s_setprio(0);
      __builtin_amdgcn_sched_barrier(0);
      asm volatile("s_waitcnt vmcnt(4)" ::: "memory");
      __builtin_amdgcn_s_barrier();
      __builtin_amdgcn_sched_barrier(0);
    }
  }
  // Peeled kt = 15 (no staging; drain at mid-boundary).
  {
    const int base_rd = 65536;  // 15 & 1
#pragma unroll
    for (int kk = 0; kk < 2; ++kk) {
      s8v af[8], bfv[4];
#pragma unroll
      for (int m = 0; m < 8; ++m)
        af[m] = *(const s8v*)(smem + base_rd + kk * 16384 + (arow + m * 16) * 64 + p_read);
#pragma unroll
      for (int n = 0; n < 4; ++n)
        bfv[n] = *(const s8v*)(smem + base_rd + 32768 + kk * 16384 + (brow + n * 16) * 64 + p_read);
      __builtin_amdgcn_s_setprio(1);
#pragma unroll
      for (int m = 0; m < 8; ++m)
#pragma unroll
        for (int n = 0; n < 4; ++n)
          acc[m][n] = mfma_bf16(af[m], bfv[n], acc[m][n]);
      __builtin_amdgcn_s_setprio(0);
      if (kk == 0) {
        __builtin_amdgcn_sched_barrier(0);
        asm volatile("s_waitcnt vmcnt(0)" ::: "memory");
        __builtin_amdgcn_s_barrier();
        __builtin_amdgcn_sched_barrier(0);
      }
    }
  }
  // Epilogue
  const int r4 = (l >> 4) * 4;
#pragma unroll
  for (int n = 0; n < 4; ++n) {
    const int gc = ncol0 + wc * 64 + n * 16 + fr;
    const float bb = bias[gc];
#pragma unroll
    for (int m = 0; m < 8; ++m)
#pragma unroll
      for (int i = 0; i < 4; ++i) {
        const int gr = mrow0 + wr * 128 + m * 16 + r4 + i;
        C[(size_t)gr * N3 + gc] = f2bf(acc[m][n][i] + bb);
      }
  }
}

// ================= pooling pipeline =================
template <int GATED>
__global__ __launch_bounds__(256) void plog_k(const unsigned short* __restrict__ QKV,
                                              const float* __restrict__ wvec,
                                              const float* __restrict__ bias,
                                              float* __restrict__ L, int off) {
  const int t = threadIdx.x;
  const int rg = blockIdx.x * 4 + (t >> 6);
  const int l = t & 63;
  const size_t base = (size_t)rg * N3 + off;
  u16x8 v0 = *(const u16x8*)(QKV + base + l * 16);
  u16x8 v1 = *(const u16x8*)(QKV + base + l * 16 + 8);
  const int h = l >> 2;
  const float* w;
  if (GATED) w = wvec + (((size_t)(rg >> 12) * 16 + h) * 64) + (l & 3) * 16;
  else       w = wvec + (l & 3) * 16;
  float d = 0.f;
#pragma unroll
  for (int j = 0; j < 8; ++j) d += bf2f(v0[j]) * w[j];
#pragma unroll
  for (int j = 0; j < 8; ++j) d += bf2f(v1[j]) * w[8 + j];
  d += __shfl_xor(d, 1); d += __shfl_xor(d, 2);
  if ((l & 3) == 0) L[(size_t)rg * 16 + h] = (d + bias[0]) * 0.125f;
}

__global__ __launch_bounds__(256) void pstats_k(const float* __restrict__ L,
                                                float* __restrict__ stats) {
  __shared__ float redm[4], reds[4];
  const int t = threadIdx.x;
  const int bh = blockIdx.x;
  const int b = bh >> 4, h = bh & 15;
  float vals[16];
  float mx = -1e30f;
#pragma unroll
  for (int j = 0; j < 16; ++j) {
    vals[j] = L[((size_t)b * S_ + t + j * 256) * 16 + h];
    mx = fmaxf(mx, vals[j]);
  }
  for (int off = 32; off; off >>= 1) mx = fmaxf(mx, __shfl_xor(mx, off));
  if ((t & 63) == 0) redm[t >> 6] = mx;
  __syncthreads();
  mx = fmaxf(fmaxf(redm[0], redm[1]), fmaxf(redm[2], redm[3]));
  float sm = 0.f;
#pragma unroll
  for (int j = 0; j < 16; ++j) sm += expf(vals[j] - mx);
  for (int off = 32; off; off >>= 1) sm += __shfl_xor(sm, off);
  if ((t & 63) == 0) reds[t >> 6] = sm;
  __syncthreads();
  if (t == 0) {
    stats[bh * 2] = mx;
    stats[bh * 2 + 1] = 1.f / (reds[0] + reds[1] + reds[2] + reds[3]);
  }
}

__global__ __launch_bounds__(256) void psum_k(const unsigned short* __restrict__ QKV,
                                              const float* __restrict__ L,
                                              const float* __restrict__ stats,
                                              float* __restrict__ pg, int off) {
  __shared__ float red2[256];
  const int t = threadIdx.x;
  const int c = blockIdx.x, bh = blockIdx.y;
  const int b = bh >> 4, h = bh & 15;
  const float MX = stats[bh * 2], INV = stats[bh * 2 + 1];
  const int w = t >> 6, d = t & 63;
  float acc = 0.f;
  const int s0 = c * 256 + w * 64;
#pragma unroll 4
  for (int i = 0; i < 64; ++i) {
    const size_t row = (size_t)b * S_ + s0 + i;
    const float a = expf(L[row * 16 + h] - MX) * INV;
    acc += a * bf2f(QKV[row * N3 + off + h * 64 + d]);
  }
  red2[t] = acc;
  __syncthreads();
  if (t < 64)
    pg[((size_t)bh * 16 + c) * 64 + t] =
        red2[t] + red2[64 + t] + red2[128 + t] + red2[192 + t];
}

__global__ __launch_bounds__(256) void predq_k(const float* __restrict__ pg,
                                               const float* __restrict__ wkl,
                                               float* __restrict__ gq,
                                               float* __restrict__ weffK) {
  const int idx = blockIdx.x * 256 + threadIdx.x;
  const int bh = idx >> 6, d = idx & 63;
  float s = 0.f;
#pragma unroll
  for (int c = 0; c < 16; ++c) s += pg[((size_t)bh * 16 + c) * 64 + d];
  gq[idx] = s;
  weffK[idx] = s * wkl[d];
}

__global__ __launch_bounds__(256) void predk_k(const float* __restrict__ pg,
                                               const float* __restrict__ gq,
                                               float* __restrict__ gk) {
  const int idx = blockIdx.x * 256 + threadIdx.x;
  const int bh = idx >> 6, d = idx & 63;
  float s = 0.f;
#pragma unroll
  for (int c = 0; c < 16; ++c) s += pg[((size_t)bh * 16 + c) * 64 + d];
  gk[idx] = gq[idx] * s;
}

// ================= final: out = q + (v*gk) @ Wr + br =================
__global__ __launch_bounds__(256) void final_out(const unsigned short* __restrict__ QKV,
                                                 const float* __restrict__ gk,
                                                 const float* __restrict__ Wr,
                                                 const float* __restrict__ br,
                                                 float* __restrict__ out) {
  __shared__ unsigned short Us[128 * 64];
  __shared__ float wrs[64 * 64];
  __shared__ float gks[64];
  const int t = threadIdx.x;
  const int w = t >> 6, l = t & 63;
  const int bh = blockIdx.y, sc = blockIdx.x;
  const int b = bh >> 4, h = bh & 15;
  const int s0 = sc * 128;
  if (t < 64) gks[t] = gk[bh * 64 + t];
#pragma unroll
  for (int i = 0; i < 16; ++i) wrs[i * 256 + t] = Wr[i * 256 + t];
  __syncthreads();
  const int rsub = t >> 3, csub = (t & 7) * 8;
  const size_t vbase = (((size_t)b * S_ + s0) * N3) + 2048 + h * 64;
#pragma unroll
  for (int i = 0; i < 4; ++i) {
    int r = i * 32 + rsub;
    u16x8 v = *(const u16x8*)(QKV + vbase + (size_t)r * N3 + csub);
    u16x8 u;
#pragma unroll
    for (int j = 0; j < 8; ++j) u[j] = f2bf(bf2f(v[j]) * gks[csub + j]);
    *(u16x8*)&Us[r * 64 + csub] = u;
  }
  const int fr = l & 15, fk = (l >> 4) * 8;
  s8v bfrag[2][4];
#pragma unroll
  for (int ks = 0; ks < 2; ++ks)
#pragma unroll
    for (int nf = 0; nf < 4; ++nf) {
      s8v tmp;
#pragma unroll
      for (int j = 0; j < 8; ++j)
        tmp[j] = (short)f2bf(wrs[(ks * 32 + fk + j) * 64 + nf * 16 + fr]);
      bfrag[ks][nf] = tmp;
    }
  __syncthreads();
  f32x4 acc[2][4];
#pragma unroll
  for (int rf = 0; rf < 2; ++rf)
#pragma unroll
    for (int nf = 0; nf < 4; ++nf) acc[rf][nf] = f32x4{0.f, 0.f, 0.f, 0.f};
#pragma unroll
  for (int ks = 0; ks < 2; ++ks) {
    s8v af[2];
#pragma unroll
    for (int rf = 0; rf < 2; ++rf)
      af[rf] = *(const s8v*)&Us[(w * 32 + rf * 16 + fr) * 64 + ks * 32 + fk];
#pragma unroll
    for (int rf = 0; rf < 2; ++rf)
#pragma unroll
      for (int nf = 0; nf < 4; ++nf)
        acc[rf][nf] = mfma_bf16(af[rf], bfrag[ks][nf], acc[rf][nf]);
  }
  const int r4 = (l >> 4) * 4;
#pragma unroll
  for (int rf = 0; rf < 2; ++rf)
#pragma unroll
    for (int nf = 0; nf < 4; ++nf)
#pragma unroll
      for (int i = 0; i < 4; ++i) {
        int srow = s0 + w * 32 + rf * 16 + r4 + i;
        int dcol = nf * 16 + fr;
        size_t row = (size_t)b * S_ + srow;
        float q = bf2f(QKV[row * N3 + h * 64 + dcol]);
        out[row * 1024 + h * 64 + dcol] = q + acc[rf][nf][i] + br[dcol];
      }
}

extern "C" void kernel_launch(void* const* d_in, const int* in_sizes, int n_in,
                              void* d_out, int out_size, void* d_ws, size_t ws_size,
                              hipStream_t stream) {
  const float* X   = (const float*)d_in[0];
  const float* Wq  = (const float*)d_in[1];
  const float* bq  = (const float*)d_in[2];
  const float* Wk  = (const float*)d_in[3];
  const float* bk  = (const float*)d_in[4];
  const float* Wv  = (const float*)d_in[5];
  const float* bv  = (const float*)d_in[6];
  const float* wql = (const float*)d_in[7];
  const float* bql = (const float*)d_in[8];
  const float* wkl = (const float*)d_in[9];
  const float* bkl = (const float*)d_in[10];
  const float* Wr  = (const float*)d_in[11];
  const float* br  = (const float*)d_in[12];
  float* out = (float*)d_out;

  char* ws = (char*)d_ws;
  unsigned short* Xb  = (unsigned short*)ws;
  unsigned short* WT  = (unsigned short*)(ws + 67108864);
  float* bcat         = (float*)(ws + 73400320);
  unsigned short* QKV = (unsigned short*)(ws + 73412608);
  float* Lq    = (float*)(ws + 0);
  float* Lk    = (float*)(ws + 2097152);
  float* pgq   = (float*)(ws + 4194304);
  float* pgk   = (float*)(ws + 4718592);
  float* statsQ= (float*)(ws + 5242880);
  float* statsK= (float*)(ws + 5246976);
  float* gq    = (float*)(ws + 6291456);
  float* weffK = (float*)(ws + 6324224);
  float* gk    = (float*)(ws + 6356992);

  // Unconditional (harness forbids call-count-dependent behavior); host-side, capture-safe.
  hipFuncSetAttribute(reinterpret_cast<const void*>(gemm256),
                      hipFuncAttributeMaxDynamicSharedMemorySize, 131072);

  hipLaunchKernelGGL(cvt_bf16_k, dim3(16384), dim3(256), 0, stream, X, Xb);
  hipLaunchKernelGGL(packWT_k, dim3(16, 16, 3), dim3(256), 0, stream, Wq, Wk, Wv, WT);
  hipLaunchKernelGGL(packbias_k, dim3(12), dim3(256), 0, stream, bq, bk, bv, bcat);
  hipLaunchKernelGGL(gemm256, dim3(1536), dim3(512), 131072, stream, Xb, WT, bcat, QKV);

  hipLaunchKernelGGL((plog_k<0>), dim3(8192), dim3(256), 0, stream, QKV, wql, bql, Lq, 0);
  hipLaunchKernelGGL(pstats_k, dim3(128), dim3(256), 0, stream, Lq, statsQ);
  hipLaunchKernelGGL(psum_k, dim3(16, 128), dim3(256), 0, stream, QKV, Lq, statsQ, pgq, 0);
  hipLaunchKernelGGL(predq_k, dim3(32), dim3(256), 0, stream, pgq, wkl, gq, weffK);
  hipLaunchKernelGGL((plog_k<1>), dim3(8192), dim3(256), 0, stream, QKV, weffK, bkl, Lk, 1024);
  hipLaunchKernelGGL(pstats_k, dim3(128), dim3(256), 0, stream, Lk, statsK);
  hipLaunchKernelGGL(psum_k, dim3(16, 128), dim3(256), 0, stream, QKV, Lk, statsK, pgk, 1024);
  hipLaunchKernelGGL(predk_k, dim3(32), dim3(256), 0, stream, pgk, gq, gk);

  hipLaunchKernelGGL(final_out, dim3(32, 128), dim3(256), 0, stream, QKV, gk, Wr, br, out);
}

// Round 8
// 601.539 us; speedup vs baseline: 2.0213x; 1.0374x over previous
//
#include <hip/hip_runtime.h>
#include <stdint.h>

// Problem constants
#define B_   8
#define S_   4096
#define D_   1024
#define H_   16
#define HD_  64
#define M_   (B_ * S_)   // 32768 rows
#define N3   (3 * D_)    // 3072 fused QKV cols

using f32x4 = __attribute__((ext_vector_type(4))) float;
using s8v   = __attribute__((ext_vector_type(8))) short;
using u16x8 = __attribute__((ext_vector_type(8))) unsigned short;
using bf8v  = __attribute__((ext_vector_type(8))) __bf16;

static __device__ __forceinline__ float bf2f(unsigned short u) {
  union { unsigned int i; float f; } x; x.i = ((unsigned int)u) << 16; return x.f;
}
static __device__ __forceinline__ unsigned short f2bf(float f) {
  union { float f; unsigned int i; } x; x.f = f;
  unsigned int r = x.i + 0x7fffu + ((x.i >> 16) & 1u);
  return (unsigned short)(r >> 16);
}

template <typename T>
static __device__ __forceinline__ auto mfma_try(T a, T b, f32x4 c, int)
    -> decltype(__builtin_amdgcn_mfma_f32_16x16x32_bf16(a, b, c, 0, 0, 0)) {
  return __builtin_amdgcn_mfma_f32_16x16x32_bf16(a, b, c, 0, 0, 0);
}
template <typename T>
static __device__ __forceinline__ f32x4 mfma_try(T a, T b, f32x4 c, long) {
  return __builtin_amdgcn_mfma_f32_16x16x32_bf16(
      __builtin_bit_cast(bf8v, a), __builtin_bit_cast(bf8v, b), c, 0, 0, 0);
}
static __device__ __forceinline__ f32x4 mfma_bf16(s8v a, s8v b, f32x4 c) {
  return mfma_try(a, b, c, 0);
}

static __device__ __forceinline__ void gl_lds16(const void* g, void* l) {
  __builtin_amdgcn_global_load_lds(
      (const __attribute__((address_space(1))) void*)g,
      (__attribute__((address_space(3))) void*)l, 16, 0, 0);
}

// ================= X fp32 -> bf16 =================
__global__ __launch_bounds__(256) void cvt_bf16_k(const float* __restrict__ in,
                                                  unsigned short* __restrict__ out) {
  size_t i = ((size_t)blockIdx.x * 256 + threadIdx.x) * 8;
  f32x4 a = *(const f32x4*)(in + i);
  f32x4 b = *(const f32x4*)(in + i + 4);
  u16x8 o;
#pragma unroll
  for (int j = 0; j < 4; ++j) { o[j] = f2bf(a[j]); o[4 + j] = f2bf(b[j]); }
  *(u16x8*)(out + i) = o;
}

// ================= pack W^T (bf16) =================
__global__ __launch_bounds__(256) void packWT_k(const float* __restrict__ Wq,
                                                const float* __restrict__ Wk,
                                                const float* __restrict__ Wv,
                                                unsigned short* __restrict__ WT) {
  __shared__ unsigned short tile[64][65];
  const float* W = blockIdx.z == 0 ? Wq : (blockIdx.z == 1 ? Wk : Wv);
  unsigned short* O = WT + (size_t)blockIdx.z * 1024 * 1024;
  const int tk = blockIdx.x * 64, tn = blockIdx.y * 64;
  const int t = threadIdx.x;
#pragma unroll
  for (int i = 0; i < 16; ++i) {
    int idx = i * 256 + t; int r = idx >> 6, c = idx & 63;
    tile[c][r] = f2bf(W[(size_t)(tk + r) * 1024 + tn + c]);
  }
  __syncthreads();
#pragma unroll
  for (int i = 0; i < 16; ++i) {
    int idx = i * 256 + t; int r = idx >> 6, c = idx & 63;
    O[(size_t)(tn + r) * 1024 + tk + c] = tile[r][c];
  }
}

__global__ void packbias_k(const float* __restrict__ bq, const float* __restrict__ bk,
                           const float* __restrict__ bv, float* __restrict__ bcat) {
  int i = blockIdx.x * 256 + threadIdx.x;
  if (i < 1024) bcat[i] = bq[i];
  else if (i < 2048) bcat[i] = bk[i - 1024];
  else if (i < 3072) bcat[i] = bv[i - 2048];
}

// ================= 256x256 4-phase counted-vmcnt GEMM =================
// LDS: 2 bufs x 64KB. Buf: A [kh][256 rows][4 slots x16B] at +0; B same at +32768.
// Half h of a tile = rows [h*128, h*128+128), both kh. Stage slots per tile:
// P1:Ah0 P2:Bh0 P3:Bh1 P4:Ah1; reads: P1 {A mh0, B nh0}, P2 {B nh1}, P3 {A mh1}.
// Wave (wr,wc) owns rows {wr*64..+64} u {128+wr*64..+64}, cols {wc*32..+32} u {128+wc*32..+32}
// so quadrant (mh,nh) touches exactly halves (Ah_mh, Bh_nh).
static __device__ __forceinline__ void stage_half(const unsigned short* __restrict__ g,
                                                  int grow0, int kt, int h,
                                                  char* region, int t) {
#pragma unroll
  for (int j = 0; j < 2; ++j) {
    const int li = j * 512 + t;            // 0..1023
    const int kh = li >> 9, idx = li & 511;
    const int row = h * 128 + (idx >> 2), slot = idx & 3;
    const unsigned short* src = g + (size_t)(grow0 + row) * 1024 + kt * 64 + kh * 32 + slot * 8;
    gl_lds16(src, region + kh * 16384 + h * 8192 + idx * 16);
  }
}

#define VMCNT(n) asm volatile("s_waitcnt vmcnt(" #n ")" ::: "memory")
#define BAR()    { __builtin_amdgcn_s_barrier(); __builtin_amdgcn_sched_barrier(0); }

__global__ __launch_bounds__(512, 2) void gemm256(const unsigned short* __restrict__ A,
                                                  const unsigned short* __restrict__ BT,
                                                  const float* __restrict__ bias,
                                                  unsigned short* __restrict__ C) {
  extern __shared__ char smem[];   // 131072
  const int t = threadIdx.x;
  const int w = t >> 6, l = t & 63;
  // XCD chunking: 8 chunks of 192; within chunk bx fastest (A-panel reuse x12 per XCD)
  const int cpx = gridDim.x >> 3;
  const int lid = ((int)blockIdx.x & 7) * cpx + ((int)blockIdx.x >> 3);
  const int by = lid / 12, bx = lid - by * 12;
  const int mrow0 = by * 256, ncol0 = bx * 256;
  const int wr = w >> 2, wc = w & 3;
  const int fr = l & 15;
  const int pr = (l >> 4) * 16;
  const int arow0 = wr * 64 + fr;   // + mh*128 + mf*16
  const int brow0 = wc * 32 + fr;   // + nh*128 + nf*16

  f32x4 acc[8][4];
#pragma unroll
  for (int m = 0; m < 8; ++m)
#pragma unroll
    for (int n = 0; n < 4; ++n) acc[m][n] = f32x4{0.f, 0.f, 0.f, 0.f};

  // prologue: tile 0 into buf0, slot order Ah0,Bh0,Bh1,Ah1
  stage_half(A,  mrow0, 0, 0, smem, t);
  stage_half(BT, ncol0, 0, 0, smem + 32768, t);
  stage_half(BT, ncol0, 0, 1, smem + 32768, t);
  stage_half(A,  mrow0, 0, 1, smem, t);
  VMCNT(4);   // Ah0, Bh0 landed
  BAR();

  s8v a0[8], a1[8], b0[4], b1[4];

#define RD_A(dst, MH, bufp)                                                        \
  _Pragma("unroll") for (int mf = 0; mf < 4; ++mf)                                 \
  _Pragma("unroll") for (int ks = 0; ks < 2; ++ks)                                 \
    dst[mf * 2 + ks] = *(const s8v*)((bufp) + ks * 16384 +                         \
                        ((MH) * 128 + arow0 + mf * 16) * 64 + pr);
#define RD_B(dst, NH, bufp)                                                        \
  _Pragma("unroll") for (int nf = 0; nf < 2; ++nf)                                 \
  _Pragma("unroll") for (int ks = 0; ks < 2; ++ks)                                 \
    dst[nf * 2 + ks] = *(const s8v*)((bufp) + 32768 + ks * 16384 +                 \
                        ((NH) * 128 + brow0 + nf * 16) * 64 + pr);
#define MFMA_Q(av, bv, MH, NH)                                                     \
  __builtin_amdgcn_s_setprio(1);                                                   \
  _Pragma("unroll") for (int mf = 0; mf < 4; ++mf)                                 \
  _Pragma("unroll") for (int nf = 0; nf < 2; ++nf)                                 \
  _Pragma("unroll") for (int ks = 0; ks < 2; ++ks)                                 \
    acc[(MH) * 4 + mf][(NH) * 2 + nf] =                                            \
        mfma_bf16(av[mf * 2 + ks], bv[nf * 2 + ks], acc[(MH) * 4 + mf][(NH) * 2 + nf]); \
  __builtin_amdgcn_s_setprio(0);                                                   \
  __builtin_amdgcn_sched_barrier(0);

  for (int kt = 0; kt < 15; ++kt) {
    char* buf  = smem + (kt & 1) * 65536;
    char* nbuf = smem + ((kt + 1) & 1) * 65536;
    // P1
    RD_A(a0, 0, buf); RD_B(b0, 0, buf);
    stage_half(A, mrow0, kt + 1, 0, nbuf, t);
    BAR();
    MFMA_Q(a0, b0, 0, 0);
    VMCNT(4); BAR();
    // P2
    RD_B(b1, 1, buf);
    stage_half(BT, ncol0, kt + 1, 0, nbuf + 32768, t);
    BAR();
    MFMA_Q(a0, b1, 0, 1);
    VMCNT(4); BAR();
    // P3
    RD_A(a1, 1, buf);
    stage_half(BT, ncol0, kt + 1, 1, nbuf + 32768, t);
    BAR();
    MFMA_Q(a1, b1, 1, 1);
    VMCNT(4); BAR();
    // P4
    stage_half(A, mrow0, kt + 1, 1, nbuf, t);
    BAR();
    MFMA_Q(a1, b0, 1, 0);
    VMCNT(4); BAR();
  }
  // tail kt = 15 (buf1, no staging)
  {
    char* buf = smem + 65536;
    RD_A(a0, 0, buf); RD_B(b0, 0, buf);
    BAR();
    MFMA_Q(a0, b0, 0, 0);
    VMCNT(2); BAR();          // retire Bh1 (staged kt14 P3)
    RD_B(b1, 1, buf);
    BAR();
    MFMA_Q(a0, b1, 0, 1);
    VMCNT(0); BAR();          // retire Ah1 (staged kt14 P4)
    RD_A(a1, 1, buf);
    MFMA_Q(a1, b1, 1, 1);
    MFMA_Q(a1, b0, 1, 0);
  }
  // epilogue
  const int r4 = (l >> 4) * 4;
#pragma unroll
  for (int mh = 0; mh < 2; ++mh)
#pragma unroll
    for (int mf = 0; mf < 4; ++mf)
#pragma unroll
      for (int nh = 0; nh < 2; ++nh)
#pragma unroll
        for (int nf = 0; nf < 2; ++nf) {
          const int gc = ncol0 + nh * 128 + wc * 32 + nf * 16 + fr;
          const int grb = mrow0 + mh * 128 + wr * 64 + mf * 16 + r4;
          const float bb = bias[gc];
#pragma unroll
          for (int i = 0; i < 4; ++i)
            C[(size_t)(grb + i) * N3 + gc] = f2bf(acc[mh * 4 + mf][nh * 2 + nf][i] + bb);
        }
#undef RD_A
#undef RD_B
#undef MFMA_Q
}

// ================= pooling pipeline =================
template <int GATED>
__global__ __launch_bounds__(256) void plog_k(const unsigned short* __restrict__ QKV,
                                              const float* __restrict__ wvec,
                                              const float* __restrict__ bias,
                                              float* __restrict__ L, int off) {
  const int t = threadIdx.x;
  const int rg = blockIdx.x * 4 + (t >> 6);
  const int l = t & 63;
  const size_t base = (size_t)rg * N3 + off;
  u16x8 v0 = *(const u16x8*)(QKV + base + l * 16);
  u16x8 v1 = *(const u16x8*)(QKV + base + l * 16 + 8);
  const int h = l >> 2;
  const float* w;
  if (GATED) w = wvec + (((size_t)(rg >> 12) * 16 + h) * 64) + (l & 3) * 16;
  else       w = wvec + (l & 3) * 16;
  float d = 0.f;
#pragma unroll
  for (int j = 0; j < 8; ++j) d += bf2f(v0[j]) * w[j];
#pragma unroll
  for (int j = 0; j < 8; ++j) d += bf2f(v1[j]) * w[8 + j];
  d += __shfl_xor(d, 1); d += __shfl_xor(d, 2);
  if ((l & 3) == 0) L[(size_t)rg * 16 + h] = (d + bias[0]) * 0.125f;
}

// partial weighted sums with inline softmax stats. grid (16 chunks, 128 bh)
__global__ __launch_bounds__(256) void psum_k(const unsigned short* __restrict__ QKV,
                                              const float* __restrict__ L,
                                              float* __restrict__ pg, int off) {
  __shared__ float redm[4], reds[4], red2[256];
  const int t = threadIdx.x;
  const int c = blockIdx.x, bh = blockIdx.y;
  const int b = bh >> 4, h = bh & 15;
  // stats over full (b,h) row (redundant per chunk; L2-resident)
  float vals[16];
  float mx = -1e30f;
#pragma unroll
  for (int j = 0; j < 16; ++j) {
    vals[j] = L[((size_t)b * S_ + t + j * 256) * 16 + h];
    mx = fmaxf(mx, vals[j]);
  }
  for (int off2 = 32; off2; off2 >>= 1) mx = fmaxf(mx, __shfl_xor(mx, off2));
  if ((t & 63) == 0) redm[t >> 6] = mx;
  __syncthreads();
  mx = fmaxf(fmaxf(redm[0], redm[1]), fmaxf(redm[2], redm[3]));
  float sm = 0.f;
#pragma unroll
  for (int j = 0; j < 16; ++j) sm += expf(vals[j] - mx);
  for (int off2 = 32; off2; off2 >>= 1) sm += __shfl_xor(sm, off2);
  if ((t & 63) == 0) reds[t >> 6] = sm;
  __syncthreads();
  const float MX = mx;
  const float INV = 1.f / (reds[0] + reds[1] + reds[2] + reds[3]);
  const int w = t >> 6, d = t & 63;
  float acc = 0.f;
  const int s0 = c * 256 + w * 64;
#pragma unroll 4
  for (int i = 0; i < 64; ++i) {
    const size_t row = (size_t)b * S_ + s0 + i;
    const float a = expf(L[row * 16 + h] - MX) * INV;
    acc += a * bf2f(QKV[row * N3 + off + h * 64 + d]);
  }
  red2[t] = acc;
  __syncthreads();
  if (t < 64)
    pg[((size_t)bh * 16 + c) * 64 + t] =
        red2[t] + red2[64 + t] + red2[128 + t] + red2[192 + t];
}

__global__ __launch_bounds__(256) void predq_k(const float* __restrict__ pg,
                                               const float* __restrict__ wkl,
                                               float* __restrict__ gq,
                                               float* __restrict__ weffK) {
  const int idx = blockIdx.x * 256 + threadIdx.x;
  const int bh = idx >> 6, d = idx & 63;
  float s = 0.f;
#pragma unroll
  for (int c = 0; c < 16; ++c) s += pg[((size_t)bh * 16 + c) * 64 + d];
  gq[idx] = s;
  weffK[idx] = s * wkl[d];
}

__global__ __launch_bounds__(256) void predk_k(const float* __restrict__ pg,
                                               const float* __restrict__ gq,
                                               float* __restrict__ gk) {
  const int idx = blockIdx.x * 256 + threadIdx.x;
  const int bh = idx >> 6, d = idx & 63;
  float s = 0.f;
#pragma unroll
  for (int c = 0; c < 16; ++c) s += pg[((size_t)bh * 16 + c) * 64 + d];
  gk[idx] = gq[idx] * s;
}

// ================= final: out = q + (v*gk) @ Wr + br =================
__global__ __launch_bounds__(256) void final_out(const unsigned short* __restrict__ QKV,
                                                 const float* __restrict__ gk,
                                                 const float* __restrict__ Wr,
                                                 const float* __restrict__ br,
                                                 float* __restrict__ out) {
  __shared__ unsigned short Us[128 * 64];
  __shared__ float wrs[64 * 64];
  __shared__ float gks[64];
  const int t = threadIdx.x;
  const int w = t >> 6, l = t & 63;
  const int bh = blockIdx.y, sc = blockIdx.x;
  const int b = bh >> 4, h = bh & 15;
  const int s0 = sc * 128;
  if (t < 64) gks[t] = gk[bh * 64 + t];
#pragma unroll
  for (int i = 0; i < 16; ++i) wrs[i * 256 + t] = Wr[i * 256 + t];
  __syncthreads();
  const int rsub = t >> 3, csub = (t & 7) * 8;
  const size_t vbase = (((size_t)b * S_ + s0) * N3) + 2048 + h * 64;
#pragma unroll
  for (int i = 0; i < 4; ++i) {
    int r = i * 32 + rsub;
    u16x8 v = *(const u16x8*)(QKV + vbase + (size_t)r * N3 + csub);
    u16x8 u;
#pragma unroll
    for (int j = 0; j < 8; ++j) u[j] = f2bf(bf2f(v[j]) * gks[csub + j]);
    *(u16x8*)&Us[r * 64 + csub] = u;
  }
  const int fr = l & 15, fk = (l >> 4) * 8;
  s8v bfrag[2][4];
#pragma unroll
  for (int ks = 0; ks < 2; ++ks)
#pragma unroll
    for (int nf = 0; nf < 4; ++nf) {
      s8v tmp;
#pragma unroll
      for (int j = 0; j < 8; ++j)
        tmp[j] = (short)f2bf(wrs[(ks * 32 + fk + j) * 64 + nf * 16 + fr]);
      bfrag[ks][nf] = tmp;
    }
  __syncthreads();
  f32x4 acc[2][4];
#pragma unroll
  for (int rf = 0; rf < 2; ++rf)
#pragma unroll
    for (int nf = 0; nf < 4; ++nf) acc[rf][nf] = f32x4{0.f, 0.f, 0.f, 0.f};
#pragma unroll
  for (int ks = 0; ks < 2; ++ks) {
    s8v af[2];
#pragma unroll
    for (int rf = 0; rf < 2; ++rf)
      af[rf] = *(const s8v*)&Us[(w * 32 + rf * 16 + fr) * 64 + ks * 32 + fk];
#pragma unroll
    for (int rf = 0; rf < 2; ++rf)
#pragma unroll
      for (int nf = 0; nf < 4; ++nf)
        acc[rf][nf] = mfma_bf16(af[rf], bfrag[ks][nf], acc[rf][nf]);
  }
  const int r4 = (l >> 4) * 4;
#pragma unroll
  for (int rf = 0; rf < 2; ++rf)
#pragma unroll
    for (int nf = 0; nf < 4; ++nf)
#pragma unroll
      for (int i = 0; i < 4; ++i) {
        int srow = s0 + w * 32 + rf * 16 + r4 + i;
        int dcol = nf * 16 + fr;
        size_t row = (size_t)b * S_ + srow;
        float q = bf2f(QKV[row * N3 + h * 64 + dcol]);
        out[row * 1024 + h * 64 + dcol] = q + acc[rf][nf][i] + br[dcol];
      }
}

extern "C" void kernel_launch(void* const* d_in, const int* in_sizes, int n_in,
                              void* d_out, int out_size, void* d_ws, size_t ws_size,
                              hipStream_t stream) {
  const float* X   = (const float*)d_in[0];
  const float* Wq  = (const float*)d_in[1];
  const float* bq  = (const float*)d_in[2];
  const float* Wk  = (const float*)d_in[3];
  const float* bk  = (const float*)d_in[4];
  const float* Wv  = (const float*)d_in[5];
  const float* bv  = (const float*)d_in[6];
  const float* wql = (const float*)d_in[7];
  const float* bql = (const float*)d_in[8];
  const float* wkl = (const float*)d_in[9];
  const float* bkl = (const float*)d_in[10];
  const float* Wr  = (const float*)d_in[11];
  const float* br  = (const float*)d_in[12];
  float* out = (float*)d_out;

  char* ws = (char*)d_ws;
  unsigned short* Xb  = (unsigned short*)ws;
  unsigned short* WT  = (unsigned short*)(ws + 67108864);
  float* bcat         = (float*)(ws + 73400320);
  unsigned short* QKV = (unsigned short*)(ws + 73412608);
  float* Lq    = (float*)(ws + 0);
  float* Lk    = (float*)(ws + 2097152);
  float* pgq   = (float*)(ws + 4194304);
  float* pgk   = (float*)(ws + 4718592);
  float* gq    = (float*)(ws + 6291456);
  float* weffK = (float*)(ws + 6324224);
  float* gk    = (float*)(ws + 6356992);

  hipFuncSetAttribute(reinterpret_cast<const void*>(gemm256),
                      hipFuncAttributeMaxDynamicSharedMemorySize, 131072);

  hipLaunchKernelGGL(cvt_bf16_k, dim3(16384), dim3(256), 0, stream, X, Xb);
  hipLaunchKernelGGL(packWT_k, dim3(16, 16, 3), dim3(256), 0, stream, Wq, Wk, Wv, WT);
  hipLaunchKernelGGL(packbias_k, dim3(12), dim3(256), 0, stream, bq, bk, bv, bcat);
  hipLaunchKernelGGL(gemm256, dim3(1536), dim3(512), 131072, stream, Xb, WT, bcat, QKV);

  hipLaunchKernelGGL((plog_k<0>), dim3(8192), dim3(256), 0, stream, QKV, wql, bql, Lq, 0);
  hipLaunchKernelGGL(psum_k, dim3(16, 128), dim3(256), 0, stream, QKV, Lq, pgq, 0);
  hipLaunchKernelGGL(predq_k, dim3(32), dim3(256), 0, stream, pgq, wkl, gq, weffK);
  hipLaunchKernelGGL((plog_k<1>), dim3(8192), dim3(256), 0, stream, QKV, weffK, bkl, Lk, 1024);
  hipLaunchKernelGGL(psum_k, dim3(16, 128), dim3(256), 0, stream, QKV, Lk, pgk, 1024);
  hipLaunchKernelGGL(predk_k, dim3(32), dim3(256), 0, stream, pgk, gq, gk);

  hipLaunchKernelGGL(final_out, dim3(32, 128), dim3(256), 0, stream, QKV, gk, Wr, br, out);
}